// Round 8
// baseline (258.165 us; speedup 1.0000x reference)
//
#include <hip/hip_runtime.h>
#include <hip/hip_bf16.h>

#define NN      50000
#define DEG     16
#define FDIM    128
#define BPW     16      // rows per wave (one 16-row m-tile, fully wave-private)
#define OSTR    136     // private transpose-buffer row stride (shorts), 16B-aligned rows
// ws layout (shorts): We1t[128][288] | We2t,Wx1t,Wv1t,Wh1t,Wh2t each [128][128]
#define OFF_WE1 0
#define OFF_WE2 36864
#define OFF_WX1 53248
#define OFF_WV1 69632
#define OFF_WH1 86016
#define OFF_WH2 102400
#define WS_SHORTS 118784

typedef short v8s  __attribute__((ext_vector_type(8)));
typedef float v4f  __attribute__((ext_vector_type(4)));

__device__ __forceinline__ float fast_tanh(float xv) {
    float ax = fabsf(xv);
    float e2 = __expf(2.0f * ax);
    float r  = 1.0f - 2.0f / (e2 + 1.0f);
    return copysignf(r, xv);
}

__device__ __forceinline__ short f2bf(float f) {   // RNE float->bf16
    union { float f; unsigned u; } a; a.f = f;
    unsigned r = a.u + 0x7fffu + ((a.u >> 16) & 1u);
    return (short)(unsigned short)(r >> 16);
}

__device__ __forceinline__ v8s pack8(float4 a, float4 b) {
    v8s s = { f2bf(a.x), f2bf(a.y), f2bf(a.z), f2bf(a.w),
              f2bf(b.x), f2bf(b.y), f2bf(b.z), f2bf(b.w) };
    return s;
}

// -------- weight prep: fp32 [K][128] -> bf16 Wt [128][KPAD] in ws --------
__global__ __launch_bounds__(256) void prep_weights(
    const float* __restrict__ We1, const float* __restrict__ We2,
    const float* __restrict__ Wx1, const float* __restrict__ Wv1,
    const float* __restrict__ Wh1, const float* __restrict__ Wh2,
    short* __restrict__ wbuf)
{
    int idx = blockIdx.x * 256 + threadIdx.x;
    if (idx < 128 * 288) {                       // We1t with zero K-pad 273..287
        int c = idx / 288, k = idx % 288;
        wbuf[OFF_WE1 + idx] = (k < 273) ? f2bf(We1[k * FDIM + c]) : (short)0;
        return;
    }
    idx -= 128 * 288;
    if (idx < 5 * 16384) {
        int layer = idx / 16384, r = idx % 16384;
        int c = r / 128, k = r % 128;
        const float* W = (layer == 0) ? We2 : (layer == 1) ? Wx1 :
                         (layer == 2) ? Wv1 : (layer == 3) ? Wh1 : Wh2;
        wbuf[OFF_WE2 + layer * 16384 + c * 128 + k] = f2bf(W[k * FDIM + c]);
    }
}

// MFMA over one 16-row tile x 128 cols: acc[ft] += A(af) x W-tile, B inline.
// A: lane (lm=l&15) = row, lk=l>>4 gives k-slice. B: lane lm = col, lk = k-slice.
template<int KSTEPS>
__device__ __forceinline__ void mfma_16rows(const v8s* af, const short* __restrict__ Wt,
                                            int lm, int lk, v4f acc[8])
{
#pragma unroll
    for (int ft = 0; ft < 8; ++ft) {
        const short* bp = Wt + (size_t)(ft * 16 + lm) * (KSTEPS * 32) + lk * 8;
#pragma unroll
        for (int kc = 0; kc < KSTEPS; ++kc) {
            v8s b = *(const v8s*)(bp + kc * 32);
            acc[ft] = __builtin_amdgcn_mfma_f32_16x16x32_bf16(af[kc], b, acc[ft], 0, 0, 0);
        }
    }
}

__device__ __forceinline__ void acc_zero8(v4f acc[8]) {
    v4f z = {0.f, 0.f, 0.f, 0.f};
#pragma unroll
    for (int ft = 0; ft < 8; ++ft) acc[ft] = z;
}

// C-layout (col=l&15, row=lk*4+r) -> tanh -> bf16 -> private LDS [16][OSTR]
__device__ __forceinline__ void epi_transpose(v4f acc[8], short* tb,
                                              const float* __restrict__ b,
                                              int lm, int lk)
{
#pragma unroll
    for (int ft = 0; ft < 8; ++ft) {
        const int col = ft * 16 + lm;
        const float bias = b[col];
#pragma unroll
        for (int r = 0; r < 4; ++r)
            tb[(lk * 4 + r) * OSTR + col] = f2bf(fast_tanh(acc[ft][r] + bias));
    }
}

// read A-frags for a K=128 layer from the private transpose buffer
__device__ __forceinline__ void load_af_lds(const short* tb, int lm, int lk, v8s af[4])
{
#pragma unroll
    for (int kc = 0; kc < 4; ++kc)
        af[kc] = *(const v8s*)(tb + lm * OSTR + kc * 32 + lk * 8);
}

// 16-lane-group (col-axis) reduce: every lane gets the group total
__device__ __forceinline__ float red16(float s) {
    s += __shfl_xor(s, 1, 64);
    s += __shfl_xor(s, 2, 64);
    s += __shfl_xor(s, 4, 64);
    s += __shfl_xor(s, 8, 64);
    return s;
}

// -------- edge kernel: 16 edges per wave, NO barriers, no shared staging ----
__global__ __launch_bounds__(256, 3) void edge_kernel(
    const float* __restrict__ h, const float* __restrict__ x,
    const float* __restrict__ ea, const int* __restrict__ cols,
    const short* __restrict__ wbuf,
    const float* __restrict__ be1, const float* __restrict__ be2,
    const float* __restrict__ bx1,
    const float* __restrict__ Wx2, const float* __restrict__ bx2,
    float* __restrict__ msum, float* __restrict__ exsum)
{
    __shared__ __align__(16) short tbuf[4][BPW * OSTR];   // wave-private slices

    const int tid = threadIdx.x;
    const int l   = tid & 63, w = tid >> 6;
    const int wv  = blockIdx.x * 4 + w;       // global wave id
    const int e0  = wv * BPW;
    if (e0 >= NN) return;                     // wave-uniform exit (no barriers used)
    const int lm = l & 15, lk = l >> 4;
    short* tb = &tbuf[w][0];

    const int i  = e0 >> 4;                   // all 16 edges share source node i
    const int jj = cols[e0 + lm];             // per-row dest node

    // dr / sdiff for row lm (computed redundantly across lk groups)
    float dx = x[i * 3 + 0] - x[jj * 3 + 0];
    float dy = x[i * 3 + 1] - x[jj * 3 + 1];
    float dz = x[i * 3 + 2] - x[jj * 3 + 2];
    const float dr    = dx * dx + dy * dy + dz * dz;
    const float sdiff = dx + dy + dz;

    // ---- build L1 A-fragments straight from global (K=288) ----
    v8s af[9];
#pragma unroll
    for (int kc = 0; kc < 4; ++kc) {          // k 0..127: h_i (wave-uniform row)
        const float4* p = (const float4*)(h + (size_t)i * FDIM + kc * 32 + lk * 8);
        af[kc] = pack8(p[0], p[1]);
    }
#pragma unroll
    for (int kc = 0; kc < 4; ++kc) {          // k 128..255: h_j (per-row gather)
        const float4* p = (const float4*)(h + (size_t)jj * FDIM + kc * 32 + lk * 8);
        af[kc + 4] = pack8(p[0], p[1]);
    }
    {                                         // k 256..287: [dr | ea(16) | 0-pad]
        const float* earow = ea + (size_t)(e0 + lm) * 16;
        float4 ea0 = *(const float4*)(earow);
        float4 ea1 = *(const float4*)(earow + 4);
        float4 ea2 = *(const float4*)(earow + 8);
        float4 ea3 = *(const float4*)(earow + 12);
        v8s z = {0,0,0,0,0,0,0,0};
        if (lk == 0) {
            v8s s = { f2bf(dr), f2bf(ea0.x), f2bf(ea0.y), f2bf(ea0.z),
                      f2bf(ea0.w), f2bf(ea1.x), f2bf(ea1.y), f2bf(ea1.z) };
            af[8] = s;
        } else if (lk == 1) {
            v8s s = { f2bf(ea1.w), f2bf(ea2.x), f2bf(ea2.y), f2bf(ea2.z),
                      f2bf(ea2.w), f2bf(ea3.x), f2bf(ea3.y), f2bf(ea3.z) };
            af[8] = s;
        } else if (lk == 2) {
            v8s s = { f2bf(ea3.w), 0, 0, 0, 0, 0, 0, 0 };
            af[8] = s;
        } else af[8] = z;
    }

    v4f acc[8];
    // L1: t1 = tanh(attrs @ We1 + be1) -> private LDS
    acc_zero8(acc);
    mfma_16rows<9>(af, wbuf + OFF_WE1, lm, lk, acc);
    epi_transpose(acc, tb, be1, lm, lk);

    // L2: m = tanh(t1 @ We2 + be2) -> same buffer (in-wave program order is safe);
    //     msum row-partials straight from registers
    v8s am[4];
    load_af_lds(tb, lm, lk, am);
    acc_zero8(acc);
    mfma_16rows<4>(am, wbuf + OFF_WE2, lm, lk, acc);
    {
        float p[4] = {0.f, 0.f, 0.f, 0.f};
#pragma unroll
        for (int ft = 0; ft < 8; ++ft) {
            const int col = ft * 16 + lm;
            const float bias = be2[col];
#pragma unroll
            for (int r = 0; r < 4; ++r) {
                float t = fast_tanh(acc[ft][r] + bias);
                tb[(lk * 4 + r) * OSTR + col] = f2bf(t);
                p[r] += t;
            }
        }
#pragma unroll
        for (int r = 0; r < 4; ++r) {
            float s = red16(p[r]);
            if (lm == 0) msum[e0 + lk * 4 + r] = s;
        }
    }

    // L3: t2 = tanh(m @ Wx1 + bx1); phi partial = t2 . Wx2 (registers only)
    load_af_lds(tb, lm, lk, am);
    acc_zero8(acc);
    mfma_16rows<4>(am, wbuf + OFF_WX1, lm, lk, acc);
    {
        float p[4] = {0.f, 0.f, 0.f, 0.f};
#pragma unroll
        for (int ft = 0; ft < 8; ++ft) {
            const int col = ft * 16 + lm;
            const float bias = bx1[col];
            const float wx = Wx2[col];
#pragma unroll
            for (int r = 0; r < 4; ++r)
                p[r] += fast_tanh(acc[ft][r] + bias) * wx;
        }
        const float bxx = bx2[0];
#pragma unroll
        for (int r = 0; r < 4; ++r) {
            float s  = red16(p[r]);
            float sd = __shfl(sdiff, lk * 4 + r, 64);   // sdiff for row lk*4+r
            if (lm == 0) exsum[e0 + lk * 4 + r] = fast_tanh(s + bxx) * sd;
        }
    }
}

// -------- node kernel: 16 nodes per wave, NO barriers --------
__global__ __launch_bounds__(256, 3) void node_kernel(
    const float* __restrict__ h, const float* __restrict__ x,
    const float* __restrict__ vel, const int* __restrict__ cols,
    const short* __restrict__ wbuf,
    const float* __restrict__ bv1, const float* __restrict__ Wv2,
    const float* __restrict__ bv2,
    const float* __restrict__ bh1, const float* __restrict__ Wh1f,
    const float* __restrict__ bh2,
    const float* __restrict__ msum, const float* __restrict__ exsum,
    float* __restrict__ out_h, float* __restrict__ out_x, float* __restrict__ out_v)
{
    __shared__ __align__(16) short tbuf[4][BPW * OSTR];

    const int tid = threadIdx.x;
    const int l   = tid & 63, w = tid >> 6;
    const int wv  = blockIdx.x * 4 + w;
    const int n0  = wv * BPW;
    if (n0 >= NN) return;
    const int lm = l & 15, lk = l >> 4;
    short* tb = &tbuf[w][0];

    // ---- gather m_i / media for row lm: edges [16n, 16n+16), 4 per lk group ----
    float ms = 0.f, ex = 0.f;
#pragma unroll
    for (int t = 0; t < 4; ++t) {
        int c = cols[(size_t)(n0 + lm) * DEG + lk * 4 + t];
        ms += msum[c];
        ex += exsum[c];
    }
    ms += __shfl_xor(ms, 16, 64); ms += __shfl_xor(ms, 32, 64);  // all lanes: mi[lm]
    ex += __shfl_xor(ex, 16, 64); ex += __shfl_xor(ex, 32, 64);
    const float media = ex * (1.0f / 16.0f);                     // media[lm]

    // ---- A-fragments of h rows straight from global ----
    v8s ah[4];
#pragma unroll
    for (int kc = 0; kc < 4; ++kc) {
        const float4* p = (const float4*)(h + (size_t)(n0 + lm) * FDIM + kc * 32 + lk * 8);
        ah[kc] = pack8(p[0], p[1]);
    }

    v4f acc[8];
    // Lv1: tv = tanh(h @ Wv1 + bv1); phi_v partial = tv . Wv2 (registers only)
    acc_zero8(acc);
    mfma_16rows<4>(ah, wbuf + OFF_WV1, lm, lk, acc);
    float pv[4];
    {
        float p[4] = {0.f, 0.f, 0.f, 0.f};
#pragma unroll
        for (int ft = 0; ft < 8; ++ft) {
            const int col = ft * 16 + lm;
            const float bias = bv1[col];
            const float wvv = Wv2[col];
#pragma unroll
            for (int r = 0; r < 4; ++r)
                p[r] += fast_tanh(acc[ft][r] + bias) * wvv;
        }
#pragma unroll
        for (int r = 0; r < 4; ++r) pv[r] = red16(p[r]);   // phi_v for row lk*4+r
    }

    // Lh1: th = tanh([h|m_i] @ Wh1 + bh1) -> private LDS
    acc_zero8(acc);
    mfma_16rows<4>(ah, wbuf + OFF_WH1, lm, lk, acc);
    {
        float mi_r[4];
#pragma unroll
        for (int r = 0; r < 4; ++r) mi_r[r] = __shfl(ms, lk * 4 + r, 64);
        const float* w128 = Wh1f + (size_t)FDIM * FDIM;
#pragma unroll
        for (int ft = 0; ft < 8; ++ft) {
            const int col = ft * 16 + lm;
            const float bias = bh1[col], wr = w128[col];
#pragma unroll
            for (int r = 0; r < 4; ++r)
                tb[(lk * 4 + r) * OSTR + col] =
                    f2bf(fast_tanh(acc[ft][r] + bias + mi_r[r] * wr));
        }
    }

    // Lh2: h_new = th @ Wh2 + bh2 -> global fp32 (direct from C layout)
    v8s am[4];
    load_af_lds(tb, lm, lk, am);
    acc_zero8(acc);
    mfma_16rows<4>(am, wbuf + OFF_WH2, lm, lk, acc);
#pragma unroll
    for (int ft = 0; ft < 8; ++ft) {
        const int col = ft * 16 + lm;
        const float bias = bh2[col];
#pragma unroll
        for (int r = 0; r < 4; ++r)
            out_h[(size_t)(n0 + lk * 4 + r) * FDIM + col] = acc[ft][r] + bias;
    }

    // vel_new / x_new: rows lk*4+r, component lm (lanes lm<3 write)
    const float bvv = bv2[0];
#pragma unroll
    for (int r = 0; r < 4; ++r) {
        float media_r = __shfl(media, lk * 4 + r, 64);
        if (lm < 3) {
            int n = n0 + lk * 4 + r;
            float vv = vel[(size_t)n * 3 + lm] * (pv[r] + bvv) + media_r;
            out_v[(size_t)n * 3 + lm] = vv;
            out_x[(size_t)n * 3 + lm] = x[(size_t)n * 3 + lm] + vv;
        }
    }
}

extern "C" void kernel_launch(void* const* d_in, const int* in_sizes, int n_in,
                              void* d_out, int out_size, void* d_ws, size_t ws_size,
                              hipStream_t stream)
{
    (void)in_sizes; (void)n_in; (void)out_size; (void)ws_size;
    const float* h    = (const float*)d_in[0];
    const float* x    = (const float*)d_in[1];
    const float* vel  = (const float*)d_in[2];
    const float* ea   = (const float*)d_in[3];
    const int*   cols = (const int*)d_in[5];
    const float* We1 = (const float*)d_in[6];  const float* be1 = (const float*)d_in[7];
    const float* We2 = (const float*)d_in[8];  const float* be2 = (const float*)d_in[9];
    const float* Wx1 = (const float*)d_in[10]; const float* bx1 = (const float*)d_in[11];
    const float* Wx2 = (const float*)d_in[12]; const float* bx2 = (const float*)d_in[13];
    const float* Wh1 = (const float*)d_in[14]; const float* bh1 = (const float*)d_in[15];
    const float* Wh2 = (const float*)d_in[16]; const float* bh2 = (const float*)d_in[17];
    const float* Wv1 = (const float*)d_in[18]; const float* bv1 = (const float*)d_in[19];
    const float* Wv2 = (const float*)d_in[20]; const float* bv2 = (const float*)d_in[21];

    short* wbuf  = (short*)d_ws;
    float* msum  = (float*)((char*)d_ws + WS_SHORTS * sizeof(short));
    float* exsum = msum + NN;
    float* out_h = (float*)d_out;
    float* out_x = out_h + (size_t)NN * FDIM;
    float* out_v = out_x + (size_t)NN * 3;

    dim3 block(256);
    prep_weights<<<dim3((WS_SHORTS + 255) / 256), block, 0, stream>>>(
        We1, We2, Wx1, Wv1, Wh1, Wh2, wbuf);
    const int nwaves = (NN + BPW - 1) / BPW;          // 3125
    dim3 grid((nwaves + 3) / 4);                      // 782 blocks x 4 waves
    edge_kernel<<<grid, block, 0, stream>>>(h, x, ea, cols, wbuf,
                                            be1, be2, bx1, Wx2, bx2, msum, exsum);
    node_kernel<<<grid, block, 0, stream>>>(h, x, vel, cols, wbuf,
                                            bv1, Wv2, bv2, bh1, Wh1, bh2,
                                            msum, exsum, out_h, out_x, out_v);
}